// Round 8
// baseline (95.293 us; speedup 1.0000x reference)
//
#include <hip/hip_runtime.h>

// Problem constants: batch=4, seq=4096, dim=1024, fp32.
#define BATCH 4
#define SEQ   4096
#define DIM   1024
#define DIM4  (DIM / 4)      // 256 float4 lanes across dim
#define NC    512            // number of time chunks
#define CHUNK (SEQ / NC)     // 8 timesteps per chunk

typedef float vf4 __attribute__((ext_vector_type(4)));

__device__ __forceinline__ vf4 vfma4(vf4 a, vf4 h, vf4 b) {
    vf4 r;
    r.x = fmaf(a.x, h.x, b.x);
    r.y = fmaf(a.y, h.y, b.y);
    r.z = fmaf(a.z, h.z, b.z);
    r.w = fmaf(a.w, h.w, b.w);
    return r;
}

// ---------------- Phase 1: chunk summaries (P = prod a, Q = local scan) ----------------
// A,B are the L3-resident working set (128 MB); read with REGULAR loads so they cache.
__global__ __launch_bounds__(256) void ssm_phase1(const vf4* __restrict__ A,
                                                  const vf4* __restrict__ B,
                                                  vf4* __restrict__ P,
                                                  vf4* __restrict__ Q) {
    const int c  = blockIdx.x % NC;
    const int b  = blockIdx.x / NC;
    const int d4 = threadIdx.x;   // 0..DIM4-1

    const size_t base = ((size_t)b * SEQ + (size_t)c * CHUNK) * DIM4 + d4;

    vf4 p = A[base];
    vf4 q = B[base];
#pragma unroll
    for (int t = 1; t < CHUNK; ++t) {
        vf4 a  = A[base + (size_t)t * DIM4];
        vf4 bb = B[base + (size_t)t * DIM4];
        q = vfma4(a, q, bb);
        p = p * a;
    }

    const size_t w = ((size_t)b * NC + c) * DIM4 + d4;
    P[w] = p;
    Q[w] = q;
}

// ---------------- Phase 2: Kogge-Stone scan over NC chunk summaries per channel --------
__global__ __launch_bounds__(NC) void ssm_phase2(vf4* __restrict__ PH,   // in: P, out: carry-in H
                                                 const vf4* __restrict__ Q) {
    const int b  = blockIdx.x / DIM4;
    const int d4 = blockIdx.x % DIM4;
    const int c  = threadIdx.x;      // chunk index 0..NC-1

    __shared__ vf4 sp[NC];
    __shared__ vf4 sq[NC];

    const size_t idx = ((size_t)b * NC + c) * DIM4 + d4;
    vf4 p = PH[idx];
    vf4 q = Q[idx];
    sp[c] = p;
    sq[c] = q;
    __syncthreads();

    for (int off = 1; off < NC; off <<= 1) {
        vf4 pp, qq;
        const bool has = (c >= off);
        if (has) { pp = sp[c - off]; qq = sq[c - off]; }
        __syncthreads();
        if (has) {
            q = vfma4(p, qq, q);   // q = p_cur * q_prev + q_cur
            p = p * pp;            // p = p_cur * p_prev
            sp[c] = p;
            sq[c] = q;
        }
        __syncthreads();
    }

    vf4 h = (c == 0) ? (vf4)(0.f) : sq[c - 1];
    PH[idx] = h;
}

// ---------------- Phase 3: seeded re-scan, y = c * h ----------------
// A,B: regular loads (L3-hot, keep cached). C: nontemporal loads (read-once —
// do NOT evict A/B from L3). Y: nontemporal stores (write-once).
__global__ __launch_bounds__(256) void ssm_phase3(const vf4* __restrict__ A,
                                                  const vf4* __restrict__ B,
                                                  const vf4* __restrict__ C,
                                                  const vf4* __restrict__ H,
                                                  vf4* __restrict__ Y) {
    const int c  = blockIdx.x % NC;
    const int b  = blockIdx.x / NC;
    const int d4 = threadIdx.x;

    const size_t base = ((size_t)b * SEQ + (size_t)c * CHUNK) * DIM4 + d4;

    vf4 h = H[((size_t)b * NC + c) * DIM4 + d4];

#pragma unroll
    for (int t = 0; t < CHUNK; ++t) {
        vf4 a  = A[base + (size_t)t * DIM4];
        vf4 bb = B[base + (size_t)t * DIM4];
        vf4 cc = __builtin_nontemporal_load(&C[base + (size_t)t * DIM4]);
        h = vfma4(a, h, bb);
        __builtin_nontemporal_store(cc * h, &Y[base + (size_t)t * DIM4]);
    }
}

extern "C" void kernel_launch(void* const* d_in, const int* in_sizes, int n_in,
                              void* d_out, int out_size, void* d_ws, size_t ws_size,
                              hipStream_t stream) {
    // setup_inputs order: x (unused), B, C, A — all fp32 [4, 4096, 1024]
    const vf4* B = (const vf4*)d_in[1];
    const vf4* C = (const vf4*)d_in[2];
    const vf4* A = (const vf4*)d_in[3];
    vf4* Y = (vf4*)d_out;

    // Workspace: P (reused as carry H) then Q, each BATCH*NC*DIM floats = 8 MB.
    vf4* P = (vf4*)d_ws;
    vf4* Q = P + (size_t)BATCH * NC * DIM4;

    ssm_phase1<<<BATCH * NC, 256, 0, stream>>>(A, B, P, Q);

    ssm_phase2<<<BATCH * DIM4, NC, 0, stream>>>(P, Q);

    ssm_phase3<<<BATCH * NC, 256, 0, stream>>>(A, B, C, P, Y);
}